// Round 8
// baseline (1147.502 us; speedup 1.0000x reference)
//
#include <hip/hip_runtime.h>

typedef float  f32x4  __attribute__((ext_vector_type(4)));
typedef short  s16x8  __attribute__((ext_vector_type(8)));
typedef short  s16x4  __attribute__((ext_vector_type(4)));
typedef _Float16 f16;

namespace {
constexpr int NN = 127, IDIM = 300, HD = 150;
constexpr int NT = 640, NW = 10;     // big_gemm: 10 waves, wave w = cols 16w+l of each gate
constexpr int LNT = 320, LNW = 5;    // lights: 5 waves x 2 col-triples
constexpr int BCS = 40;              // B col stride (shorts): 80 B, 16B-aligned, 2-way banks
constexpr int SLAB_SH = 19456;       // B slab: 480*40=19200 content + pad = 38 KiB
constexpr int SCH = 38;              // 1-KiB staging chunks per slab
constexpr int ASTR = 40;             // A row stride (shorts)
constexpr int A_SH = 32 * ASTR;      // 1280 shorts per A buffer
constexpr int GEMM_LDS = (2 * A_SH + SLAB_SH) * 2;   // 44,032 B -> 3 blocks/CU
constexpr int CSTR = 164;            // light chs stride (shorts)

constexpr int W_SH = 10 * SLAB_SH;   // 194,560 shorts
constexpr int U_SH = 480 * 160;      // plain [col][k]
constexpr int F_SH = 160 * 160;

// ws: c_all f16 [4096][126][150] (node-1 indexed) | iuo_all f16 [4096][63][456] | slabs
constexpr size_t C_N   = (size_t)4096 * 126 * HD;
constexpr size_t IUO_N = (size_t)4096 * 63 * 456;

__device__ __forceinline__ short f2bf(float f) {
    union { __bf16 b; short s; } u; u.b = (__bf16)f; return u.s;
}
__device__ __forceinline__ float bf2f(short s) {
    union { float f; unsigned u; } v; v.u = ((unsigned)(unsigned short)s) << 16; return v.f;
}
__device__ __forceinline__ float sig_(float x)  { return 1.0f / (1.0f + __expf(-x)); }
__device__ __forceinline__ float tanh_(float x) { float e = __expf(2.0f * x); return 1.0f - 2.0f / (e + 1.0f); }
__device__ __forceinline__ s16x4 cvt4(float a,float b,float c,float d) {
    return s16x4{ f2bf(a), f2bf(b), f2bf(c), f2bf(d) };
}
__device__ __forceinline__ s16x8 cat(s16x4 lo, s16x4 hi) {
    return __builtin_shufflevector(lo, hi, 0,1,2,3,4,5,6,7);
}
__device__ __forceinline__ f32x4 MFMA(s16x8 a, s16x8 b, f32x4 c) {
    return __builtin_amdgcn_mfma_f32_16x16x32_bf16(a, b, c, 0, 0, 0);
}

typedef const __attribute__((address_space(1))) unsigned int* gp_t;
typedef __attribute__((address_space(3))) unsigned int* lp_t;
__device__ __forceinline__ void stage_slab(const short* g, short* l, int nch, int wv, int ln) {
    const char* gb = (const char*)g;
    char* lb = (char*)l;
    for (int c = wv; c < nch; c += NW)
        __builtin_amdgcn_global_load_lds((gp_t)(gb + c * 1024 + ln * 16),
                                         (lp_t)(lb + c * 1024 + ln * 16), 16, 0, 0);
}
} // namespace

// -------- one-time weight prep: W -> 10 K-chunk slabs [480][40]; U,F plain [col][160] --------
__global__ __launch_bounds__(256)
void prep_w(const float* __restrict__ Wiuo, const float* __restrict__ Uiuo,
            const float* __restrict__ Ufw, short* __restrict__ dst) {
    int i = blockIdx.x * 256 + threadIdx.x;
    short v = 0;
    if (i < W_SH) {
        int kc = i / SLAB_SH, r = i - kc * SLAB_SH;
        if (r < 480 * BCS) {
            int col = r / BCS, j = r - col * BCS;
            int g = col / 160, cp = col - g * 160, k = kc * 32 + j;
            if (cp < HD && j < 32 && k < IDIM) v = f2bf(Wiuo[(size_t)(g*HD + cp)*IDIM + k]);
        }
        dst[i] = v;
    } else if (i < W_SH + U_SH) {
        int q = i - W_SH;
        int col = q / 160, k = q - col * 160;
        int g = col / 160, cp = col - g * 160;
        if (cp < HD && k < HD) v = f2bf(Uiuo[(size_t)(g*HD + cp)*HD + k]);
        dst[i] = v;
    } else if (i < W_SH + U_SH + F_SH) {
        int q = i - W_SH - U_SH;
        int col = q / 160, k = q - col * 160;
        if (col < HD && k < HD) v = f2bf(Ufw[(size_t)col*HD + k]);
        dst[i] = v;
    }
}

// -------- merged projection GEMM over ALL levels, BM=32, 3 blocks/CU target --------
// Per chunk: bar1 -> issue B stage + next-A global loads -> bar2(drain) -> 5 ds_read_b128
// + 6 MFMA -> ds_write next A. Cross-block overlap hides the drain (m114/m97 pattern).
// MFMA maps: A row=lane&15, B col=lane&15 (shared lane->k); C/D col=lane&15, row=4*(lane>>4)+reg.
__global__ __launch_bounds__(NT, 8)
void big_gemm(const float* __restrict__ x, const short* __restrict__ Wsl,
              const float* __restrict__ biuo, float* __restrict__ h_all,
              f16* __restrict__ c_all, f16* __restrict__ iuo_all)
{
    extern __shared__ short smem[];
    short* A0 = smem;
    short* A1 = A0 + A_SH;
    short* Bs = A1 + A_SH;

    const int t = threadIdx.x;
    const int wv = t >> 6, ln = t & 63, l15 = ln & 15, kg = ln >> 4;
    const int row0 = blockIdx.x * 32;

    // block-uniform level detect (row space ordered leaf-level first)
    int d = 6;
    for (int dd = 0; dd <= 5; ++dd)
        if (row0 >= 4096 * (128 - (2 << dd))) { d = dd; break; }
    const int base = 4096 * (128 - (2 << d));
    const int lg = d, mask = (1 << lg) - 1, start = (1 << lg) - 1;
    const int local0 = row0 - base;

    // A staging duty: threads 0..255, (row ar=t>>3, quad aq=t&7)
    const bool stg = (t < 256);
    const int ar = t >> 3, aq = t & 7;
    const float* xrow = nullptr;
    if (stg) {
        int lcl = local0 + ar, b = lcl >> lg, s = lcl & mask;
        xrow = x + ((size_t)b * NN + start + s) * IDIM;
    }

    // prologue: A chunk 0 (k = aq*4 .. +3 < 32, all valid)
    if (stg) {
        float4 f = *(const float4*)(xrow + aq * 4);
        *(s16x4*)&A0[ar * ASTR + aq * 4] = cvt4(f.x, f.y, f.z, f.w);
    }

    f32x4 acc[2][3] = {};
    #pragma unroll
    for (int kc = 0; kc < 10; ++kc) {
        short* Ac = (kc & 1) ? A1 : A0;
        short* An = (kc & 1) ? A0 : A1;
        __syncthreads();                       // everyone done with B(kc-1) and A writes visible
        stage_slab(Wsl + kc * SLAB_SH, Bs, SCH, wv, ln);
        float4 nxt = {0.f, 0.f, 0.f, 0.f};
        const bool nv = stg && (kc < 9);
        if (nv) {
            int k0 = (kc + 1) * 32 + aq * 4;   // kc==8 tail: aq<3 full, aq>=3 zero (300=288+12)
            if (k0 + 3 < IDIM) nxt = *(const float4*)(xrow + k0);
        }
        __syncthreads();                       // B(kc) landed (vmcnt drain; other blocks overlap)

        const short* pa0 = &Ac[l15 * ASTR + kg * 8];
        s16x8 a0 = cat(*(const s16x4*)pa0, *(const s16x4*)(pa0 + 4));
        const short* pa1 = &Ac[(16 + l15) * ASTR + kg * 8];
        s16x8 a1 = cat(*(const s16x4*)pa1, *(const s16x4*)(pa1 + 4));
        #pragma unroll
        for (int g = 0; g < 3; ++g) {
            const short* pb = &Bs[(g*160 + 16*wv + l15) * BCS + kg * 8];
            s16x8 bf = cat(*(const s16x4*)pb, *(const s16x4*)(pb + 4));
            acc[0][g] = MFMA(a0, bf, acc[0][g]);
            acc[1][g] = MFMA(a1, bf, acc[1][g]);
        }
        if (nv)
            *(s16x4*)&An[ar * ASTR + aq * 4] = cvt4(nxt.x, nxt.y, nxt.z, nxt.w);
    }

    // epilogue
    const int c = 16 * wv + l15;
    if (c < HD) {
        if (d == 6) {
            float bi = biuo[c], bu = biuo[HD + c], bo = biuo[2*HD + c];
            #pragma unroll
            for (int mt = 0; mt < 2; ++mt)
                #pragma unroll
                for (int r = 0; r < 4; ++r) {
                    int lcl = local0 + 16*mt + 4*kg + r;
                    int b = lcl >> 6, s = lcl & 63;
                    float cn = sig_(acc[mt][0][r] + bi) * tanh_(acc[mt][1][r] + bu);
                    float hn = sig_(acc[mt][2][r] + bo) * tanh_(cn);
                    h_all[((size_t)b*NN + 63 + s) * HD + c] = hn;
                    c_all[((size_t)b*126 + 62 + s) * HD + c] = (f16)cn;
                }
        } else {
            #pragma unroll
            for (int mt = 0; mt < 2; ++mt)
                #pragma unroll
                for (int r = 0; r < 4; ++r) {
                    int lcl = local0 + 16*mt + 4*kg + r;
                    int b = lcl >> lg, s = lcl & mask;
                    f16* ip = iuo_all + ((size_t)b*63 + start + s) * 456;
                    ip[c]       = (f16)acc[mt][0][r];
                    ip[152 + c] = (f16)acc[mt][1][r];
                    ip[304 + c] = (f16)acc[mt][2][r];
                }
        }
    }
}

// -------- light: per internal level. 16 parents/block, 5 waves x 2 col-triples --------
__global__ __launch_bounds__(LNT, 5)
void lvl_light(const short* __restrict__ Ubf, const short* __restrict__ Fbf,
               const float* __restrict__ biuo, const float* __restrict__ Ufb,
               const f16* __restrict__ iuo_all, f16* __restrict__ c_all,
               float* __restrict__ h_all, int start, int lg, int cstart)
{
    __shared__ short chs[2][16][CSTR];    // [child][parent][k] bf16
    __shared__ short fgs[LNW][32][34];    // per-wave f-gates [child rows][2x16 cols]

    const int t = threadIdx.x;
    const int wv = t >> 6, ln = t & 63, l15 = ln & 15, kg = ln >> 4;
    const int row0 = blockIdx.x * 16;
    const int mask = (1 << lg) - 1;
    int ct[2];
    ct[0] = 16 * (2*wv)     + l15;
    ct[1] = 16 * (2*wv + 1) + l15;

    // stage children h (fp32 -> bf16 LDS): (rc=t&31, part=t>>5), 16 k-elems per part
    {
        int rc = t & 31, part = t >> 5;       // part 0..9 covers k [0,160)
        int plane = rc >> 4, lr = rc & 15;
        int row = row0 + lr, b = row >> lg, s = row & mask;
        const float* hp = h_all + ((size_t)b*NN + cstart + 2*s + plane) * HD;
        short* dst = &chs[plane][lr][part * 16];
        if (part < 9) {
            float4 f0 = *(const float4*)(hp + part*16);
            float4 f1 = *(const float4*)(hp + part*16 + 4);
            float4 f2 = *(const float4*)(hp + part*16 + 8);
            float4 f3 = *(const float4*)(hp + part*16 + 12);
            *(s16x4*)(dst + 0)  = cvt4(f0.x, f0.y, f0.z, f0.w);
            *(s16x4*)(dst + 4)  = cvt4(f1.x, f1.y, f1.z, f1.w);
            *(s16x4*)(dst + 8)  = cvt4(f2.x, f2.y, f2.z, f2.w);
            *(s16x4*)(dst + 12) = cvt4(f3.x, f3.y, f3.z, f3.w);
        } else {    // k 144..159, valid < 150
            float4 f0 = *(const float4*)(hp + 144);
            float2 f1 = *(const float2*)(hp + 148);
            *(s16x4*)(dst + 0)  = cvt4(f0.x, f0.y, f0.z, f0.w);
            *(s16x4*)(dst + 4)  = s16x4{ f2bf(f1.x), f2bf(f1.y), 0, 0 };
            *(s16x4*)(dst + 8)  = s16x4{0,0,0,0};
            *(s16x4*)(dst + 12) = s16x4{0,0,0,0};
        }
    }
    __syncthreads();

    // F phase: f = sigmoid(ch @ F^T + b), 2 col-tiles per wave
    f32x4 facc[2][2] = {};      // [rt=child row-tile][tt]
    #pragma unroll
    for (int kc = 0; kc < 5; ++kc) {
        int ka = kc * 32 + kg * 8;
        s16x8 af[2];
        #pragma unroll
        for (int rt = 0; rt < 2; ++rt) {
            const short* p = &chs[rt][l15][ka];
            af[rt] = cat(*(const s16x4*)p, *(const s16x4*)(p + 4));
        }
        #pragma unroll
        for (int tt = 0; tt < 2; ++tt) {
            s16x8 bf = *(const s16x8*)(Fbf + (size_t)ct[tt] * 160 + ka);
            #pragma unroll
            for (int rt = 0; rt < 2; ++rt)
                facc[rt][tt] = MFMA(af[rt], bf, facc[rt][tt]);
        }
    }
    #pragma unroll
    for (int tt = 0; tt < 2; ++tt) {
        float fb_ = (ct[tt] < HD) ? Ufb[ct[tt]] : 0.0f;
        #pragma unroll
        for (int rt = 0; rt < 2; ++rt)
            #pragma unroll
            for (int r = 0; r < 4; ++r)
                fgs[wv][rt*16 + 4*kg + r][tt*16 + l15] = f2bf(sig_(facc[rt][tt][r] + fb_));
    }
    __syncthreads();

    // U phase: acc = h_tilda @ U^T
    f32x4 acc[2][3] = {};
    #pragma unroll
    for (int kc = 0; kc < 5; ++kc) {
        int ka = kc * 32 + kg * 8;
        const short* p0 = &chs[0][l15][ka];
        const short* p1 = &chs[1][l15][ka];
        s16x8 h0 = cat(*(const s16x4*)p0, *(const s16x4*)(p0 + 4));
        s16x8 h1 = cat(*(const s16x4*)p1, *(const s16x4*)(p1 + 4));
        s16x8 hs;
        #pragma unroll
        for (int e = 0; e < 8; ++e)
            hs[e] = f2bf(bf2f(h0[e]) + bf2f(h1[e]));
        #pragma unroll
        for (int tt = 0; tt < 2; ++tt)
            #pragma unroll
            for (int g = 0; g < 3; ++g) {
                s16x8 bf = *(const s16x8*)(Ubf + (size_t)(g*160 + ct[tt]) * 160 + ka);
                acc[tt][g] = MFMA(hs, bf, acc[tt][g]);
            }
    }

    // epilogue
    #pragma unroll
    for (int tt = 0; tt < 2; ++tt) {
        int c = ct[tt];
        if (c >= HD) continue;
        float bi = biuo[c], bu = biuo[HD + c], bo = biuo[2*HD + c];
        #pragma unroll
        for (int r = 0; r < 4; ++r) {
            int pl = 4*kg + r;
            int row = row0 + pl, b = row >> lg, s = row & mask;
            const f16* ip = iuo_all + ((size_t)b*63 + start + s) * 456;
            float ig = (float)ip[c]       + bi + acc[tt][0][r];
            float ug = (float)ip[152 + c] + bu + acc[tt][1][r];
            float og = (float)ip[304 + c] + bo + acc[tt][2][r];
            float f0 = bf2f(fgs[wv][pl][tt*16 + l15]);
            float f1 = bf2f(fgs[wv][16 + pl][tt*16 + l15]);
            size_t ci = (size_t)b*126 + (cstart + 2*s - 1);
            float c0 = (float)c_all[ci * HD + c];
            float c1 = (float)c_all[(ci + 1) * HD + c];
            float cn = sig_(ig) * tanh_(ug) + f0*c0 + f1*c1;
            float hn = sig_(og) * tanh_(cn);
            h_all[((size_t)b*NN + start + s) * HD + c] = hn;
            if (start > 0)   // root c never read
                c_all[((size_t)b*126 + start + s - 1) * HD + c] = (f16)cn;
        }
    }
}

extern "C" void kernel_launch(void* const* d_in, const int* in_sizes, int n_in,
                              void* d_out, int out_size, void* d_ws, size_t ws_size,
                              hipStream_t stream) {
    const float* x    = (const float*)d_in[0];
    const float* Wiuo = (const float*)d_in[1];
    const float* Uiuo = (const float*)d_in[2];
    const float* biuo = (const float*)d_in[3];
    const float* Ufw  = (const float*)d_in[4];
    const float* Ufb  = (const float*)d_in[5];
    float* h = (float*)d_out;

    f16* c_all   = (f16*)d_ws;
    f16* iuo_all = c_all + C_N;
    short* slabs = (short*)(iuo_all + IUO_N);
    const short* Wsl = slabs;
    const short* Ubf = slabs + W_SH;
    const short* Fbf = slabs + W_SH + U_SH;

    (void)hipFuncSetAttribute((const void*)big_gemm,
                              hipFuncAttributeMaxDynamicSharedMemorySize, 64 * 1024);

    prep_w<<<(W_SH + U_SH + F_SH + 255) / 256, 256, 0, stream>>>(Wiuo, Uiuo, Ufw, slabs);

    big_gemm<<<16256, NT, GEMM_LDS, stream>>>(x, Wsl, biuo, h, c_all, iuo_all);

    for (int d = 5; d >= 0; --d) {
        const int start = (1 << d) - 1, cstart = (1 << (d+1)) - 1;
        lvl_light<<<256 << d, LNT, 0, stream>>>(Ubf, Fbf, biuo, Ufb, iuo_all, c_all, h,
                                                start, d, cstart);
    }
}